// Round 4
// baseline (379.417 us; speedup 1.0000x reference)
//
#include <hip/hip_runtime.h>

// StatefulRecurrent: s_t = A*s_{t-1} + x_t (complex diagonal A), out = [Re(s),Im(s)].
// B=16, T=4096, D=512. SINGLE fused kernel, block-local chunked scan:
//   - Block owns (b, 32-d slice) x all T. 1024 threads = 64 segments x 16 d-pairs.
//   - Phase 1: each thread scans its 64-step segment (zero-init). x loads are NORMAL
//     so the 134 MB of x is allocated into L3 (256 MB) for the phase-3 re-read.
//   - __syncthreads (the only barrier; scan dependency is intra-block).
//   - Phase 2: incoming state by serial rescan of LDS aggregates (S = A^64*S + agg_j).
//   - Phase 3: replay the segment RE-READING x (same addresses -> L3 hit, ~15+ TB/s),
//     nt-store float4 per step (the 268 MB out stream must not evict x from L3).
//
// Round-3 lesson: x-in-registers at 1024 thr/block forces VGPR<=128 (16 waves must
// co-reside) -> xa[64]/xb[64] spilled to scratch = a hidden 134 MB HBM round-trip.
// This version keeps per-thread state ~45 VGPR: no spill, full residency, deep ILP.
//
// HBM traffic: 134 MB x read + 268 MB out write (+L3-resident re-read) ~ 64 us floor.

#define B_  16
#define T_  4096
#define D_  512
#define SEG 64
#define NS  (T_ / SEG)   // 64 segments
#define NDP 16           // d-pairs per block (32 consecutive d)

typedef float v2f __attribute__((ext_vector_type(2)));
typedef float v4f __attribute__((ext_vector_type(4)));

__global__ __launch_bounds__(1024) void fused_scan_kernel(
    const float* __restrict__ x,
    const float* __restrict__ Ar_g, const float* __restrict__ Ai_g,
    v4f* __restrict__ out4) {
  int tid  = threadIdx.x;
  int dp   = tid & (NDP - 1);   // d-pair within block: 16 contiguous d-pairs
  int seg  = tid >> 4;          // 0..63
  int n    = blockIdx.x;
  int dblk = n & 15;
  int b    = n >> 4;
  int d    = dblk * (2 * NDP) + dp * 2;
  int t0   = seg * SEG;

  __shared__ v4f agg[NS][NDP];  // 16 KB

  float2 Ar = *(const float2*)(Ar_g + d);
  float2 Ai = *(const float2*)(Ai_g + d);

  // ---- Phase 1: local zero-init scan; NORMAL loads warm L3 with x ----
  const v2f* xp = (const v2f*)(x + ((size_t)(b * T_ + t0)) * D_ + d);
  float s0r = 0.f, s0i = 0.f, s1r = 0.f, s1i = 0.f;
#pragma unroll 8
  for (int k = 0; k < SEG; ++k) {
    v2f xv = xp[(size_t)k * (D_ / 2)];
    float n0r = fmaf(s0r, Ar.x, fmaf(-s0i, Ai.x, xv.x));
    float n0i = fmaf(s0r, Ai.x, s0i * Ar.x);
    float n1r = fmaf(s1r, Ar.y, fmaf(-s1i, Ai.y, xv.y));
    float n1i = fmaf(s1r, Ai.y, s1i * Ar.y);
    s0r = n0r; s0i = n0i; s1r = n1r; s1i = n1i;
  }
  agg[seg][dp] = (v4f){s0r, s0i, s1r, s1i};
  __syncthreads();

  // ---- A^64 per d-component by 6 squarings ----
  float p0r = Ar.x, p0i = Ai.x, p1r = Ar.y, p1i = Ai.y;
#pragma unroll
  for (int q = 0; q < 6; ++q) {
    float t0r = p0r * p0r - p0i * p0i; float t0i = 2.f * p0r * p0i;
    float t1r = p1r * p1r - p1i * p1i; float t1i = 2.f * p1r * p1i;
    p0r = t0r; p0i = t0i; p1r = t1r; p1i = t1i;
  }

  // ---- Phase 2: incoming state S = sum_{j<seg} A^{64(seg-1-j)} agg_j (LDS rescan) ----
  // Trip count varies by <=3 within a wave -> negligible divergence.
  float S0r = 0.f, S0i = 0.f, S1r = 0.f, S1i = 0.f;
  for (int j = 0; j < seg; ++j) {
    v4f g = agg[j][dp];
    float n0r = fmaf(p0r, S0r, fmaf(-p0i, S0i, g.x));
    float n0i = fmaf(p0i, S0r, fmaf(p0r, S0i, g.y));
    float n1r = fmaf(p1r, S1r, fmaf(-p1i, S1i, g.z));
    float n1i = fmaf(p1i, S1r, fmaf(p1r, S1i, g.w));
    S0r = n0r; S0i = n0i; S1r = n1r; S1i = n1i;
  }

  // ---- Phase 3: replay from incoming state, re-reading x (L3 hit); nt-store out ----
  // out4 index: ((b*T+t)*D + d)*2 floats / 4 = (b*T+t)*(D/2) + d/2
  v4f* op = out4 + ((size_t)(b * T_ + t0)) * (D_ / 2) + (d >> 1);
#pragma unroll 8
  for (int k = 0; k < SEG; ++k) {
    v2f xv = xp[(size_t)k * (D_ / 2)];
    float n0r = fmaf(S0r, Ar.x, fmaf(-S0i, Ai.x, xv.x));
    float n0i = fmaf(S0r, Ai.x, S0i * Ar.x);
    float n1r = fmaf(S1r, Ar.y, fmaf(-S1i, Ai.y, xv.y));
    float n1i = fmaf(S1r, Ai.y, S1i * Ar.y);
    S0r = n0r; S0i = n0i; S1r = n1r; S1i = n1i;
    v4f ov = {S0r, S0i, S1r, S1i};
    __builtin_nontemporal_store(ov, op + (size_t)k * (D_ / 2));
  }
}

extern "C" void kernel_launch(void* const* d_in, const int* in_sizes, int n_in,
                              void* d_out, int out_size, void* d_ws, size_t ws_size,
                              hipStream_t stream) {
  const float* x  = (const float*)d_in[0];
  const float* Ar = (const float*)d_in[1];
  const float* Ai = (const float*)d_in[2];
  v4f* out = (v4f*)d_out;

  // 16 b x 16 d-blocks = 256 blocks x 1024 threads (1 block/CU, 16 waves/CU)
  fused_scan_kernel<<<dim3(256), dim3(1024), 0, stream>>>(x, Ar, Ai, out);
}